// Round 10
// baseline (227.392 us; speedup 1.0000x reference)
//
#include <hip/hip_runtime.h>
#include <math.h>
#include <stdint.h>

#define NEXP 48
#define NCAT 30
#define SP_TOT 13440            // 24*28*20
#define M_TOT (NCAT * SP_TOT)   // 403200
#define CPB 32                  // columns per block
#define PAD 50                  // floats/col: even -> float2-aligned; 2-way write alias (free)

// R2's proven-resident structure: 8 threads/col, 6 experts each, 32 cols/blk.
// This round: pure f32 rank compares with abs folded into VOP3 modifiers
// (no u64 keys, no materialized abs in the j-loop) -> 2 VALU ops per pair.
// Exactness: sum-of-strict-ranks == C(48,2) tie detector; any |value| tie
// falls back to exact stable u64-key ranks == jax.lax.top_k. General K.
__global__ __launch_bounds__(256) void moe_topk_contract(
    const float* __restrict__ gm, const float* __restrict__ gf,
    const float* __restrict__ se, const int* __restrict__ kptr,
    float* __restrict__ out)
{
    __shared__ __align__(8) float gv[CPB * PAD];

    const int tid     = threadIdx.x;
    const int colbase = blockIdx.x * CPB;
    const int cl      = tid >> 3;     // 0..31 column within block
    const int sub     = tid & 7;      // 0..7 expert sub-group
    const int col     = colbase + cl;
    const int K       = *kptr;

    // shape_experts for this thread's 6 experts (t-invariant, hoisted)
    float sev[6];
    #pragma unroll
    for (int ii = 0; ii < 6; ++ii)
        sev[ii] = se[(sub * 6 + ii) * M_TOT + col];

    #pragma unroll 1
    for (int t = 0; t < 2; ++t) {
        const float* __restrict__ g_ = t ? gf : gm;

        // stage raw g: 48 experts x 32 cols, coalesced (R2's proven pattern)
        #pragma unroll
        for (int rep = 0; rep < 6; ++rep) {
            const int e = rep * 8 + (tid >> 5);   // 0..47
            const int c = tid & 31;
            gv[c * PAD + e] = g_[e * M_TOT + colbase + c];
        }
        __syncthreads();

        // own 6 signed values; abs hoisted once (j-side abs is a free modifier)
        float gval[6], a[6];
        #pragma unroll
        for (int p = 0; p < 3; ++p) {
            const float2 q = *(const float2*)&gv[cl * PAD + sub * 6 + p * 2];
            gval[p * 2] = q.x; gval[p * 2 + 1] = q.y;
            a[p * 2] = fabsf(q.x); a[p * 2 + 1] = fabsf(q.y);
        }

        // strict-|.| rank: r[ii] = #{j: |g_j| > |g_ii|}
        // fabsf on the LDS operand folds into the v_cmp input modifier.
        int r0 = 0, r1 = 0, r2 = 0, r3 = 0, r4 = 0, r5 = 0;
        #pragma unroll
        for (int j2 = 0; j2 < 24; ++j2) {
            const float2 q = *(const float2*)&gv[cl * PAD + j2 * 2];
            const float jx = q.x, jy = q.y;
            r0 += (fabsf(jx) > a[0]); r0 += (fabsf(jy) > a[0]);
            r1 += (fabsf(jx) > a[1]); r1 += (fabsf(jy) > a[1]);
            r2 += (fabsf(jx) > a[2]); r2 += (fabsf(jy) > a[2]);
            r3 += (fabsf(jx) > a[3]); r3 += (fabsf(jy) > a[3]);
            r4 += (fabsf(jx) > a[4]); r4 += (fabsf(jy) > a[4]);
            r5 += (fabsf(jx) > a[5]); r5 += (fabsf(jy) > a[5]);
        }

        // tie detection: all-|.|-distinct column <=> sum of strict ranks == 1128
        int S = r0 + r1 + r2 + r3 + r4 + r5;
        S += __shfl_xor(S, 1); S += __shfl_xor(S, 2); S += __shfl_xor(S, 4);
        const bool tie = (S != 1128);

        // masked contraction + 8-lane reduce
        const int rr[6] = {r0, r1, r2, r3, r4, r5};
        float acc = 0.f;
        #pragma unroll
        for (int ii = 0; ii < 6; ++ii) {
            const float mv = (rr[ii] < K) ? gval[ii] : 0.f;
            acc = fmaf(mv, sev[ii], acc);
        }
        acc += __shfl_xor(acc, 1); acc += __shfl_xor(acc, 2); acc += __shfl_xor(acc, 4);

        if (__any(tie)) {
            // exact stable-rank fallback (|value| tie in column; ~1e-7 of cols)
            if (tie && sub == 0) {
                float accx = 0.f;
                #pragma unroll 1
                for (int i2 = 0; i2 < NEXP; ++i2) {
                    const float gi = g_[i2 * M_TOT + col];
                    const uint64_t ki =
                        ((uint64_t)(__float_as_uint(gi) & 0x7fffffffu) << 32)
                        | (uint32_t)(NEXP - 1 - i2);
                    int rx = 0;
                    #pragma unroll 1
                    for (int j3 = 0; j3 < NEXP; ++j3) {
                        const float gj = g_[j3 * M_TOT + col];
                        const uint64_t kj =
                            ((uint64_t)(__float_as_uint(gj) & 0x7fffffffu) << 32)
                            | (uint32_t)(NEXP - 1 - j3);
                        rx += (kj > ki) ? 1 : 0;
                    }
                    if (rx < K) accx = fmaf(gi, se[i2 * M_TOT + col], accx);
                }
                acc = accx;
            }
        }

        if (sub == 0) out[t * M_TOT + col] = acc;
        __syncthreads();
    }
}

// Kernel 2: in-place softmax over the category dim (stride SP_TOT).
__global__ __launch_bounds__(256) void softmax_c(float* __restrict__ out)
{
    const int q = blockIdx.x * blockDim.x + threadIdx.x;
    if (q >= 2 * SP_TOT) return;
    const int t  = q / SP_TOT;
    const int sp = q - t * SP_TOT;
    float* __restrict__ base = out + t * M_TOT + sp;

    float v[NCAT];
    float mx = -INFINITY;
    #pragma unroll
    for (int c = 0; c < NCAT; ++c) {
        v[c] = base[c * SP_TOT];
        mx = fmaxf(mx, v[c]);
    }
    float sum = 0.f;
    #pragma unroll
    for (int c = 0; c < NCAT; ++c) {
        v[c] = __expf(v[c] - mx);
        sum += v[c];
    }
    const float inv = 1.f / sum;
    #pragma unroll
    for (int c = 0; c < NCAT; ++c)
        base[c * SP_TOT] = v[c] * inv;
}

extern "C" void kernel_launch(void* const* d_in, const int* in_sizes, int n_in,
                              void* d_out, int out_size, void* d_ws, size_t ws_size,
                              hipStream_t stream) {
    const float* gm   = (const float*)d_in[0];
    const float* gf   = (const float*)d_in[1];
    const float* se   = (const float*)d_in[2];
    const int*   kptr = (const int*)d_in[3];
    float* out = (float*)d_out;

    const int grid1 = M_TOT / CPB;                 // 12600
    moe_topk_contract<<<grid1, 256, 0, stream>>>(gm, gf, se, kptr, out);

    const int grid2 = (2 * SP_TOT + 255) / 256;    // 105
    softmax_c<<<grid2, 256, 0, stream>>>(out);
}